// Round 4
// baseline (598.054 us; speedup 1.0000x reference)
//
#include <hip/hip_runtime.h>

namespace {
constexpr int R   = 32;
constexpr int R3  = R * R * R;       // 32768
constexpr int NB  = 8;
constexpr int NC  = 64;
constexpr int NP  = 65536;

// ws layout (bytes)
constexpr size_t OFF_SUM = 0;                                        // double sums[2][NB][3]
constexpr size_t OFF_MAX = 512;                                      // ull   maxsq[2][NB]
constexpr size_t OFF_CNT = 1024;                                     // int counts[NB][R3]   (1 MiB)
constexpr size_t OFF_OFF = OFF_CNT + sizeof(int) * (size_t)NB * R3;  // int offsets[NB][R3]  (1 MiB)
constexpr size_t OFF_CUR = OFF_OFF + sizeof(int) * (size_t)NB * R3;  // int cursor[NB][R3]   (1 MiB)
constexpr size_t OFF_IDX = OFF_CUR + sizeof(int) * (size_t)NB * R3;  // int idx[NB][NP]      (2 MiB)
constexpr size_t OFF_VOX = OFF_IDX + sizeof(int) * (size_t)NB * NP;  // float vox[NB][R3][NC]   (64 MiB)
constexpr size_t OFF_FT  = OFF_VOX + sizeof(float) * (size_t)NB * R3 * NC; // float fT[NB][NP][NC] (128 MiB)
constexpr size_t WS_BYTES = OFF_FT + sizeof(float) * (size_t)NB * NP * NC; // ~197 MiB total

typedef float vfloat4 __attribute__((ext_vector_type(4)));  // native clang vector (nontemporal-compatible)
} // namespace

__device__ inline double wave_sum(double v) {
#pragma unroll
  for (int o = 32; o > 0; o >>= 1) v += __shfl_down(v, o, 64);
  return v;
}
__device__ inline double wave_max(double v) {
#pragma unroll
  for (int o = 32; o > 0; o >>= 1) v = fmax(v, __shfl_down(v, o, 64));
  return v;
}

// ---- stats pass 1: per (set,b,axis) sum of coords ----
__global__ __launch_bounds__(256) void k_sum(const float* __restrict__ c1,
                                             const float* __restrict__ c2,
                                             double* __restrict__ sums) {
  constexpr int CH = 32;
  int blk = blockIdx.x;
  int chunk = blk % CH; blk /= CH;
  int axis  = blk % 3;  blk /= 3;
  int b     = blk % NB; blk /= NB;
  int set   = blk;
  const float* src = (set == 0 ? c1 : c2) + ((size_t)b * 3 + axis) * NP;
  constexpr int PER = NP / CH;                 // 2048
  int base = chunk * PER;
  double s = 0.0;
  for (int i = threadIdx.x; i < PER; i += 256) s += (double)src[base + i];
  s = wave_sum(s);
  __shared__ double red[4];
  if ((threadIdx.x & 63) == 0) red[threadIdx.x >> 6] = s;
  __syncthreads();
  if (threadIdx.x == 0) {
    double t = red[0] + red[1] + red[2] + red[3];
    atomicAdd(&sums[((size_t)set * NB + b) * 3 + axis], t);
  }
}

// ---- stats pass 2: per (set,b) max squared norm of centered coords ----
__global__ __launch_bounds__(256) void k_max(const float* __restrict__ c1,
                                             const float* __restrict__ c2,
                                             const double* __restrict__ sums,
                                             unsigned long long* __restrict__ maxs) {
  constexpr int CH = 64;
  int blk = blockIdx.x;
  int chunk = blk % CH; blk /= CH;
  int b     = blk % NB; blk /= NB;
  int set   = blk;
  const float* src = (set == 0 ? c1 : c2) + (size_t)b * 3 * NP;
  const double invN = 1.0 / (double)NP;
  double m0 = sums[((size_t)set * NB + b) * 3 + 0] * invN;
  double m1 = sums[((size_t)set * NB + b) * 3 + 1] * invN;
  double m2 = sums[((size_t)set * NB + b) * 3 + 2] * invN;
  constexpr int PER = NP / CH;                 // 1024
  int base = chunk * PER;
  double mx = 0.0;
  for (int i = threadIdx.x; i < PER; i += 256) {
    int p = base + i;
    double x = (double)src[p] - m0;
    double y = (double)src[NP + p] - m1;
    double z = (double)src[2 * NP + p] - m2;
    mx = fmax(mx, x * x + y * y + z * z);
  }
  mx = wave_max(mx);
  __shared__ double red[4];
  if ((threadIdx.x & 63) == 0) red[threadIdx.x >> 6] = mx;
  __syncthreads();
  if (threadIdx.x == 0) {
    double t = fmax(fmax(red[0], red[1]), fmax(red[2], red[3]));
    atomicMax(&maxs[set * NB + b], (unsigned long long)__double_as_longlong(t));
  }
}

// ---- voxel index of every x2 point + per-voxel counts (int atomics, 1 per point) ----
__global__ __launch_bounds__(256) void k_idx(const float* __restrict__ c2,
                                             const double* __restrict__ sums,
                                             const unsigned long long* __restrict__ maxs,
                                             int* __restrict__ counts,
                                             int* __restrict__ idxArr) {
  int lin = blockIdx.x;
  int b = lin & 7;
  int p0 = (lin >> 3) * 1024;
  const double invN = 1.0 / (double)NP;
  double scale = 2.0 * sqrt(__longlong_as_double((long long)maxs[NB + b]));
  double inv = 1.0 / scale;
  double m0 = sums[((size_t)NB + b) * 3 + 0] * invN;
  double m1 = sums[((size_t)NB + b) * 3 + 1] * invN;
  double m2 = sums[((size_t)NB + b) * 3 + 2] * invN;
  const float* cb = c2 + (size_t)b * 3 * NP;
#pragma unroll
  for (int k = 0; k < 4; k++) {
    int p = p0 + k * 256 + threadIdx.x;
    double n0 = (((double)cb[p] - m0) * inv + 0.5) * (double)R;
    double n1 = (((double)cb[NP + p] - m1) * inv + 0.5) * (double)R;
    double n2 = (((double)cb[2 * NP + p] - m2) * inv + 0.5) * (double)R;
    n0 = fmin(fmax(n0, 0.0), (double)(R - 1));
    n1 = fmin(fmax(n1, 0.0), (double)(R - 1));
    n2 = fmin(fmax(n2, 0.0), (double)(R - 1));
    int id = ((int)rint(n0) * R + (int)rint(n1)) * R + (int)rint(n2);  // round half-to-even
    idxArr[(size_t)b * NP + p] = id;
    atomicAdd(&counts[(size_t)b * R3 + id], 1);
  }
}

// ---- exclusive prefix sum over each batch's 32768 counts -> offsets (+cursor copy) ----
__global__ __launch_bounds__(1024) void k_prefix(const int* __restrict__ counts,
                                                 int* __restrict__ offs,
                                                 int* __restrict__ cur) {
  int b = blockIdx.x;
  int t = threadIdx.x;                  // 0..1023, 32 voxels each
  int lane = t & 63, w = t >> 6;        // 16 waves
  __shared__ int wtot[16];
  int base = b * R3 + t * 32;
  int c[32]; int s = 0;
#pragma unroll
  for (int k = 0; k < 32; k++) { c[k] = counts[base + k]; s += c[k]; }
  int v = s;                             // wave-inclusive scan of per-thread sums
#pragma unroll
  for (int o = 1; o < 64; o <<= 1) { int u = __shfl_up(v, o, 64); if (lane >= o) v += u; }
  if (lane == 63) wtot[w] = v;
  __syncthreads();
  if (w == 0) {
    int x = (lane < 16) ? wtot[lane] : 0;
#pragma unroll
    for (int o = 1; o < 16; o <<= 1) { int u = __shfl_up(x, o, 64); if (lane >= o) x += u; }
    if (lane < 16) wtot[lane] = x;       // inclusive scan of wave totals
  }
  __syncthreads();
  int run = v - s + (w > 0 ? wtot[w - 1] : 0);  // exclusive base for this thread
#pragma unroll
  for (int k = 0; k < 32; k++) { offs[base + k] = run; cur[base + k] = run; run += c[k]; }
}

// ---- scatter x2 feature rows into bucket order: plain 256B stores, no RMW ----
__global__ __launch_bounds__(256) void k_scatter(const float* __restrict__ f2,
                                                 const int* __restrict__ idxArr,
                                                 int* __restrict__ cur,
                                                 float* __restrict__ fT) {
  int lin = blockIdx.x;
  int b = lin & 7;                       // XCD-batch affinity
  int p0 = (lin >> 3) * 64;
  int tid = threadIdx.x;
  __shared__ int   s_pos[64];
  __shared__ float s_tile[64 * 65];

  if (tid < 64) {
    int id = idxArr[(size_t)b * NP + p0 + tid];
    s_pos[tid] = atomicAdd(&cur[(size_t)b * R3 + id], 1);  // unique slot in bucket
  }
  __syncthreads();

  const float* fb = f2 + (size_t)b * NC * NP;
#pragma unroll
  for (int i = 0; i < 16; i++) {
    int l2 = i * 256 + tid;
    int c = l2 >> 6, pl = l2 & 63;
    s_tile[pl * 65 + c] = __builtin_nontemporal_load(&fb[(size_t)c * NP + p0 + pl]);
  }
  __syncthreads();

  int w = tid >> 6, lane = tid & 63;
  float* ftb = fT + (size_t)b * NP * NC;
  for (int j = 0; j < 16; j++) {
    int pl = w * 16 + j;
    // contiguous 256B row per point, scattered destination, plain store (full lines, no RMW)
    ftb[(size_t)s_pos[pl] * NC + lane] = s_tile[pl * 65 + lane];
  }
}

// ---- streaming bucket reduce: vox[b][v][c] = mean of bucket rows (counts folded here) ----
__global__ __launch_bounds__(256) void k_reduce(const int* __restrict__ counts,
                                                const int* __restrict__ offs,
                                                const float* __restrict__ fT,
                                                float* __restrict__ vox) {
  int lin = blockIdx.x;
  int b = lin & 7;
  int v = (lin >> 3) * 4 + (threadIdx.x >> 6);   // one wave per voxel
  int lane = threadIdx.x & 63;
  int off = offs[(size_t)b * R3 + v];
  int cnt = counts[(size_t)b * R3 + v];
  const float* ftb = fT + (size_t)b * NP * NC;
  float acc = 0.0f;
  for (int i = 0; i < cnt; i++)
    acc += __builtin_nontemporal_load(&ftb[(size_t)(off + i) * NC + lane]);
  float m = (cnt > 0) ? acc / (float)cnt : 0.0f;  // == sums / max(cnt,1)
  vox[((size_t)b * R3 + v) * NC + lane] = m;      // cacheable: devox gathers from it
}

// ---- devoxelize at nc_x1 + fused x1->out concat copy (rides on gather-latency-idle BW) ----
__global__ __launch_bounds__(256) void k_devox(const float* __restrict__ c1,
                                               const double* __restrict__ sums,
                                               const unsigned long long* __restrict__ maxs,
                                               const float* __restrict__ vox,
                                               const float* __restrict__ f1,
                                               float* __restrict__ out) {
  int lin = blockIdx.x;
  int b = lin & 7;
  int t = lin >> 3;                  // 0..1279
  int q = t / 5, r = t - q * 5;
  int tid = threadIdx.x;

  if (r == 4) {
    // ---- concat part 1: out[b][0:NC][:] = x1_features, pure streaming copy ----
    int p0c = q * 256;
    int w = tid >> 6, lane = tid & 63;
    const vfloat4* s4 = (const vfloat4*)(f1 + (size_t)b * NC * NP + p0c);
    vfloat4*       d4 = (vfloat4*)(out + (size_t)b * 2 * NC * NP + p0c);
#pragma unroll
    for (int rr = 0; rr < 16; ++rr) {
      int c = w * 16 + rr;
      size_t off = (size_t)c * (NP / 4) + lane;
      __builtin_nontemporal_store(__builtin_nontemporal_load(s4 + off), d4 + off);
    }
    return;
  }

  int p0 = (q * 4 + r) * 64;
  __shared__ int   s_idx[64][8];
  __shared__ float s_w[64][8];
  __shared__ float s_tile[64 * 65];

  if (tid < 64) {
    int p = p0 + tid;
    const double invN = 1.0 / (double)NP;
    double scale = 2.0 * sqrt(__longlong_as_double((long long)maxs[b]));  // set 0 (x1)
    double inv = 1.0 / scale;
    const float* cb = c1 + (size_t)b * 3 * NP;
    double nc[3];
#pragma unroll
    for (int a = 0; a < 3; a++) {
      double mean = sums[(size_t)b * 3 + a] * invN;
      double v = (((double)cb[a * NP + p] - mean) * inv + 0.5) * (double)R;
      nc[a] = fmin(fmax(v, 0.0), (double)(R - 1));
    }
    int lo[3], hi[3];
    double d[3];
#pragma unroll
    for (int a = 0; a < 3; a++) {
      lo[a] = (int)floor(nc[a]);
      d[a]  = nc[a] - (double)lo[a];
      hi[a] = min(lo[a] + 1, R - 1);
    }
#pragma unroll
    for (int k = 0; k < 8; k++) {
      int ix = (k & 4) ? hi[0] : lo[0];
      int iy = (k & 2) ? hi[1] : lo[1];
      int iz = (k & 1) ? hi[2] : lo[2];
      double wx = (k & 4) ? d[0] : 1.0 - d[0];
      double wy = (k & 2) ? d[1] : 1.0 - d[1];
      double wz = (k & 1) ? d[2] : 1.0 - d[2];
      s_idx[tid][k] = (ix * R + iy) * R + iz;
      s_w[tid][k]   = (float)(wx * wy * wz);     // vox already holds means
    }
  }
  __syncthreads();

  const float* voxb = vox + (size_t)b * R3 * NC;
  int w = tid >> 6, lane = tid & 63;
  for (int j = 0; j < 16; j++) {
    int pl = w * 16 + j;
    float acc = 0.0f;
#pragma unroll
    for (int k = 0; k < 8; k++) {
      acc += s_w[pl][k] * voxb[(size_t)s_idx[pl][k] * NC + lane];
    }
    s_tile[pl * 65 + lane] = acc;
  }
  __syncthreads();

  float* outb = out + (size_t)b * (2 * NC) * NP;
#pragma unroll
  for (int i = 0; i < 16; i++) {
    int l2 = i * 256 + tid;
    int c = l2 >> 6, pl = l2 & 63;
    size_t pcol = (size_t)p0 + pl;
    __builtin_nontemporal_store(s_tile[pl * 65 + c], &outb[(size_t)(NC + c) * NP + pcol]);
  }
}

extern "C" void kernel_launch(void* const* d_in, const int* in_sizes, int n_in,
                              void* d_out, int out_size, void* d_ws, size_t ws_size,
                              hipStream_t stream) {
  const float* x1f = (const float*)d_in[0];
  const float* x2f = (const float*)d_in[1];
  const float* x1c = (const float*)d_in[2];
  const float* x2c = (const float*)d_in[3];
  float* out = (float*)d_out;

  char* ws = (char*)d_ws;
  double* sums             = (double*)(ws + OFF_SUM);
  unsigned long long* maxs = (unsigned long long*)(ws + OFF_MAX);
  int* cnts                = (int*)(ws + OFF_CNT);
  int* offs                = (int*)(ws + OFF_OFF);
  int* cur                 = (int*)(ws + OFF_CUR);
  int* idxA                = (int*)(ws + OFF_IDX);
  float* vox               = (float*)(ws + OFF_VOX);
  float* fT                = (float*)(ws + OFF_FT);

  // only sums/maxs/counts need zeroing (1.05 MB); offsets/cursor/idx/vox/fT fully written
  (void)hipMemsetAsync(ws, 0, OFF_OFF, stream);
  k_sum<<<2 * NB * 3 * 32, 256, 0, stream>>>(x1c, x2c, sums);
  k_max<<<2 * NB * 64, 256, 0, stream>>>(x1c, x2c, sums, maxs);
  k_idx<<<NB * (NP / 1024), 256, 0, stream>>>(x2c, sums, maxs, cnts, idxA);
  k_prefix<<<NB, 1024, 0, stream>>>(cnts, offs, cur);
  k_scatter<<<NB * (NP / 64), 256, 0, stream>>>(x2f, idxA, cur, fT);
  k_reduce<<<NB * (R3 / 4), 256, 0, stream>>>(cnts, offs, fT, vox);
  k_devox<<<NB * (NP / 64 + NP / 256), 256, 0, stream>>>(x1c, sums, maxs, vox, x1f, out);
}

// Round 8
// 514.278 us; speedup vs baseline: 1.1629x; 1.1629x over previous
//
#include <hip/hip_runtime.h>
#include <hip/hip_fp16.h>

namespace {
constexpr int R   = 32;
constexpr int R3  = R * R * R;       // 32768
constexpr int NB  = 8;
constexpr int NC  = 64;
constexpr int NP  = 65536;
constexpr int NH  = NC / 2;          // 32 half2 per voxel row (128B)

// ws layout (bytes)
constexpr size_t OFF_SUM = 0;        // double sums[2][NB][3]   (48 doubles)
constexpr size_t OFF_MAX = 512;      // ull   maxsq[2][NB]      (16)
constexpr size_t OFF_CNT = 1024;     // float counts[NB][R3]    (1 MiB)
constexpr size_t OFF_VOX = OFF_CNT + sizeof(float) * (size_t)NB * R3;
constexpr size_t WS_BYTES = OFF_VOX + 4 * (size_t)NB * R3 * NH; // ~33.6 MiB

typedef float    vfloat4 __attribute__((ext_vector_type(4)));  // native clang vectors
typedef _Float16 vhalf2  __attribute__((ext_vector_type(2)));  // (builtin-compatible)
} // namespace

__device__ inline double wave_sum(double v) {
#pragma unroll
  for (int o = 32; o > 0; o >>= 1) v += __shfl_down(v, o, 64);
  return v;
}
__device__ inline double wave_max(double v) {
#pragma unroll
  for (int o = 32; o > 0; o >>= 1) v = fmax(v, __shfl_down(v, o, 64));
  return v;
}

// packed 2xf16 global atomic add: HW GLOBAL_ATOMIC_PK_ADD_F16 (gfx90a+),
// one L2 RMW op per channel PAIR.
__device__ inline void pk_atomic_add_f16(vhalf2* addr, vhalf2 v) {
#if __has_builtin(__builtin_amdgcn_global_atomic_fadd_v2f16)
  (void)__builtin_amdgcn_global_atomic_fadd_v2f16(
      (__attribute__((address_space(1))) vhalf2*)addr, v);
#else
  asm volatile("global_atomic_pk_add_f16 %0, %1, off" :: "v"(addr), "v"(v) : "memory");
#endif
}

// ---- stats pass 1: per (set,b,axis) sum of coords ----
__global__ __launch_bounds__(256) void k_sum(const float* __restrict__ c1,
                                             const float* __restrict__ c2,
                                             double* __restrict__ sums) {
  constexpr int CH = 32;                       // chunks per (set,b,axis)
  int blk = blockIdx.x;
  int chunk = blk % CH; blk /= CH;
  int axis  = blk % 3;  blk /= 3;
  int b     = blk % NB; blk /= NB;
  int set   = blk;
  const float* src = (set == 0 ? c1 : c2) + ((size_t)b * 3 + axis) * NP;
  constexpr int PER = NP / CH;                 // 2048
  int base = chunk * PER;
  double s = 0.0;
  for (int i = threadIdx.x; i < PER; i += 256) s += (double)src[base + i];
  s = wave_sum(s);
  __shared__ double red[4];
  if ((threadIdx.x & 63) == 0) red[threadIdx.x >> 6] = s;
  __syncthreads();
  if (threadIdx.x == 0) {
    double t = red[0] + red[1] + red[2] + red[3];
    atomicAdd(&sums[((size_t)set * NB + b) * 3 + axis], t);
  }
}

// ---- stats pass 2: per (set,b) max squared norm of centered coords ----
__global__ __launch_bounds__(256) void k_max(const float* __restrict__ c1,
                                             const float* __restrict__ c2,
                                             const double* __restrict__ sums,
                                             unsigned long long* __restrict__ maxs) {
  constexpr int CH = 64;
  int blk = blockIdx.x;
  int chunk = blk % CH; blk /= CH;
  int b     = blk % NB; blk /= NB;
  int set   = blk;
  const float* src = (set == 0 ? c1 : c2) + (size_t)b * 3 * NP;
  const double invN = 1.0 / (double)NP;
  double m0 = sums[((size_t)set * NB + b) * 3 + 0] * invN;
  double m1 = sums[((size_t)set * NB + b) * 3 + 1] * invN;
  double m2 = sums[((size_t)set * NB + b) * 3 + 2] * invN;
  constexpr int PER = NP / CH;                 // 1024
  int base = chunk * PER;
  double mx = 0.0;
  for (int i = threadIdx.x; i < PER; i += 256) {
    int p = base + i;
    double x = (double)src[p] - m0;
    double y = (double)src[NP + p] - m1;
    double z = (double)src[2 * NP + p] - m2;
    mx = fmax(mx, x * x + y * y + z * z);
  }
  mx = wave_max(mx);
  __shared__ double red[4];
  if ((threadIdx.x & 63) == 0) red[threadIdx.x >> 6] = mx;
  __syncthreads();
  if (threadIdx.x == 0) {
    double t = fmax(fmax(red[0], red[1]), fmax(red[2], red[3]));
    atomicMax(&maxs[set * NB + b], (unsigned long long)__double_as_longlong(t));
  }
}

// ---- voxelize x2 (packed f16 scatter-add) + fused x1->out concat copy ----
// vox rows are vhalf2[32] (128B). One pk_add_f16 atomic per channel PAIR:
// 16.8M L2 atomic ops instead of 33.5M (measured ceiling ~86 ops/cy).
__global__ __launch_bounds__(256) void k_vox(const float* __restrict__ f2,
                                             const float* __restrict__ c2,
                                             const float* __restrict__ f1,
                                             const double* __restrict__ sums,
                                             const unsigned long long* __restrict__ maxs,
                                             float* __restrict__ counts,
                                             vhalf2* __restrict__ vox,
                                             float* __restrict__ out) {
  int lin = blockIdx.x;
  int b = lin & 7;          // consecutive blocks -> consecutive XCDs (round-robin)
  int t = lin >> 3;         // 0..1279 per batch
  int q = t / 5, r = t - q * 5;
  int tid = threadIdx.x;

  if (r == 4) {
    // ---- concat part 1: out[b][0:NC][:] = x1_features, pure streaming copy ----
    int p0c = q * 256;
    int w = tid >> 6, lane = tid & 63;
    const vfloat4* s4 = (const vfloat4*)(f1 + (size_t)b * NC * NP + p0c);
    vfloat4*       d4 = (vfloat4*)(out + (size_t)b * 2 * NC * NP + p0c);
#pragma unroll
    for (int rr = 0; rr < 16; ++rr) {
      int c = w * 16 + rr;
      size_t off = (size_t)c * (NP / 4) + lane;
      __builtin_nontemporal_store(__builtin_nontemporal_load(s4 + off), d4 + off);
    }
    return;
  }

  int p0 = (q * 4 + r) * 64;            // vox tile 0..1023
  __shared__ int   s_idx[64];
  __shared__ float s_tile[64 * 65];

  if (tid < 64) {
    int p = p0 + tid;
    const double invN = 1.0 / (double)NP;
    double scale = 2.0 * sqrt(__longlong_as_double((long long)maxs[NB + b]));
    double inv = 1.0 / scale;
    const float* cb = c2 + (size_t)b * 3 * NP;
    int vc[3];
#pragma unroll
    for (int a = 0; a < 3; a++) {
      double mean = sums[((size_t)NB + b) * 3 + a] * invN;
      double nc = (((double)cb[a * NP + p] - mean) * inv + 0.5) * (double)R;
      nc = fmin(fmax(nc, 0.0), (double)(R - 1));
      vc[a] = (int)rint(nc);                   // round half-to-even, matches jnp.round
    }
    int idx = (vc[0] * R + vc[1]) * R + vc[2];
    s_idx[tid] = idx;
    atomicAdd(&counts[(size_t)b * R3 + idx], 1.0f);
  }
  __syncthreads();

  const float* fb = f2 + (size_t)b * NC * NP;
#pragma unroll
  for (int i = 0; i < 16; i++) {
    int lin2 = i * 256 + tid;
    int c = lin2 >> 6, pl = lin2 & 63;
    // nontemporal: f2 touched exactly once; keep L2 for vox atomics
    s_tile[pl * 65 + c] = __builtin_nontemporal_load(&fb[(size_t)c * NP + p0 + pl]);
  }
  __syncthreads();

  // packed atomics: half-wave per point, lane owns channel pair (2*cp, 2*cp+1)
  int w = tid >> 6, lane = tid & 63;
  int half = lane >> 5, cp = lane & 31;
  vhalf2* voxb = vox + (size_t)b * R3 * NH;
#pragma unroll
  for (int j = 0; j < 8; j++) {
    int pl = w * 16 + j * 2 + half;
    vhalf2 v;
    v.x = (_Float16)s_tile[pl * 65 + 2 * cp];
    v.y = (_Float16)s_tile[pl * 65 + 2 * cp + 1];
    pk_atomic_add_f16(&voxb[(size_t)s_idx[pl] * NH + cp], v);
  }
}

// ---- devoxelize at nc_x1 (count-normalized on the fly); writes concat part 2 only ----
// f16 vox slab = 4 MiB/batch = one XCD L2 with the b%8 affinity -> gathers L2-resident.
__global__ __launch_bounds__(256) void k_devox(const float* __restrict__ c1,
                                               const double* __restrict__ sums,
                                               const unsigned long long* __restrict__ maxs,
                                               const float* __restrict__ counts,
                                               const vhalf2* __restrict__ vox,
                                               float* __restrict__ out) {
  int lin = blockIdx.x;
  int b = lin & 7;
  int p0 = (lin >> 3) * 64;
  __shared__ int   s_idx[64][8];
  __shared__ float s_w[64][8];
  __shared__ float s_tile[64 * 65];
  int tid = threadIdx.x;

  if (tid < 64) {
    int p = p0 + tid;
    const double invN = 1.0 / (double)NP;
    double scale = 2.0 * sqrt(__longlong_as_double((long long)maxs[b]));  // set 0 (x1)
    double inv = 1.0 / scale;
    const float* cb = c1 + (size_t)b * 3 * NP;
    double nc[3];
#pragma unroll
    for (int a = 0; a < 3; a++) {
      double mean = sums[(size_t)b * 3 + a] * invN;
      double v = (((double)cb[a * NP + p] - mean) * inv + 0.5) * (double)R;
      nc[a] = fmin(fmax(v, 0.0), (double)(R - 1));
    }
    int lo[3], hi[3];
    double d[3];
#pragma unroll
    for (int a = 0; a < 3; a++) {
      lo[a] = (int)floor(nc[a]);
      d[a]  = nc[a] - (double)lo[a];
      hi[a] = min(lo[a] + 1, R - 1);
    }
    const float* cntb = counts + (size_t)b * R3;
#pragma unroll
    for (int k = 0; k < 8; k++) {
      int ix = (k & 4) ? hi[0] : lo[0];
      int iy = (k & 2) ? hi[1] : lo[1];
      int iz = (k & 1) ? hi[2] : lo[2];
      double wx = (k & 4) ? d[0] : 1.0 - d[0];
      double wy = (k & 2) ? d[1] : 1.0 - d[1];
      double wz = (k & 1) ? d[2] : 1.0 - d[2];
      int idx = (ix * R + iy) * R + iz;
      float cnt = cntb[idx];
      s_idx[tid][k] = idx;
      s_w[tid][k]   = (float)(wx * wy * wz) / fmaxf(cnt, 1.0f);  // fold avg-normalization into weight
    }
  }
  __syncthreads();

  const vhalf2* voxb = vox + (size_t)b * R3 * NH;
  int w = tid >> 6, lane = tid & 63;
  int half = lane >> 5, cp = lane & 31;
#pragma unroll
  for (int j = 0; j < 8; j++) {
    int pl = w * 16 + j * 2 + half;
    float a0 = 0.0f, a1 = 0.0f;
#pragma unroll
    for (int k = 0; k < 8; k++) {
      // half-wave reads one 128B voxel row per corner (coalesced), L2-local
      vhalf2 h = voxb[(size_t)s_idx[pl][k] * NH + cp];
      float wt = s_w[pl][k];
      a0 += wt * (float)h.x;
      a1 += wt * (float)h.y;
    }
    s_tile[pl * 65 + 2 * cp]     = a0;
    s_tile[pl * 65 + 2 * cp + 1] = a1;
  }
  __syncthreads();

  float* outb = out + (size_t)b * (2 * NC) * NP;
#pragma unroll
  for (int i = 0; i < 16; i++) {
    int lin2 = i * 256 + tid;
    int c = lin2 >> 6, pl = lin2 & 63;
    size_t pcol = (size_t)p0 + pl;
    // concat part 2 only; nontemporal (output never re-read)
    __builtin_nontemporal_store(s_tile[pl * 65 + c], &outb[(size_t)(NC + c) * NP + pcol]);
  }
}

extern "C" void kernel_launch(void* const* d_in, const int* in_sizes, int n_in,
                              void* d_out, int out_size, void* d_ws, size_t ws_size,
                              hipStream_t stream) {
  const float* x1f = (const float*)d_in[0];
  const float* x2f = (const float*)d_in[1];
  const float* x1c = (const float*)d_in[2];
  const float* x2c = (const float*)d_in[3];
  float* out = (float*)d_out;

  char* ws = (char*)d_ws;
  double* sums             = (double*)(ws + OFF_SUM);
  unsigned long long* maxs = (unsigned long long*)(ws + OFF_MAX);
  float* cnts              = (float*)(ws + OFF_CNT);
  vhalf2* vox              = (vhalf2*)(ws + OFF_VOX);

  (void)hipMemsetAsync(ws, 0, WS_BYTES, stream);
  k_sum<<<2 * NB * 3 * 32, 256, 0, stream>>>(x1c, x2c, sums);
  k_max<<<2 * NB * 64, 256, 0, stream>>>(x1c, x2c, sums, maxs);
  // 8 batches x (1024 vox tiles + 256 copy tiles) = 10240 blocks, 1D, b = bid%8
  k_vox<<<NB * (NP / 64 + NP / 256), 256, 0, stream>>>(x2f, x2c, x1f, sums, maxs, cnts, vox, out);
  // 8 batches x 1024 tiles = 8192 blocks, 1D, b = bid%8
  k_devox<<<NB * (NP / 64), 256, 0, stream>>>(x1c, sums, maxs, cnts, vox, out);
}